// Round 5
// baseline (145.462 us; speedup 1.0000x reference)
//
#include <hip/hip_runtime.h>
#include <stdint.h>

typedef short short8 __attribute__((ext_vector_type(8)));
typedef float floatx4 __attribute__((ext_vector_type(4)));

#define NN 100000   // nodes
#define NE 800000   // edges
#define KF 128      // in_feat (K of node GEMM)
#define PC 256      // P row stride in BYTES: [0:128)=src half int8, [128:256)=dst half int8
#define BM 64       // nodes per block in node kernel
#define LDK 136     // padded LDS row stride in shorts for the A tile (free 2-way alias)

// fp32 -> bf16 (RNE)
__device__ __forceinline__ unsigned short f2bf(float x) {
  union { float f; unsigned u; } c; c.f = x;
  unsigned u = c.u + 0x7FFFu + ((c.u >> 16) & 1u);
  return (unsigned short)(u >> 16);
}
// signed byte k of u -> float
__device__ __forceinline__ float sb8(unsigned u, int k) {
  return (float)(signed char)((u >> (8 * k)) & 0xffu);
}

// ---------------------------------------------------------------------------
// Kernel 0: one-time W1 (fp32 [128][256]) -> Wcat bf16, concatenated layout,
// PRE-SWIZZLED for linear global_load_lds staging + XOR'd B-fragment reads.
//   Wcat[j][k] = (j<128) ? W1[j][k] : W1[j-128][128+k]
// Output in d_out (read by node_proj before edge_score overwrites d_out).
// ---------------------------------------------------------------------------
extern "C" __global__ void __launch_bounds__(256)
wcat_prep_kernel(const float* __restrict__ W1, unsigned short* __restrict__ Wcatb)
{
  const int idx = blockIdx.x * 256 + threadIdx.x;  // 4096 threads, 8 elems each
  const int j  = idx >> 4;          // Wcat row 0..255
  const int k8 = (idx & 15) << 3;   // k chunk start 0..120

  const int h  = j >> 7;
  const int jl = j & 127;
  const float* sp = W1 + (size_t)jl * 256 + h * 128 + k8;
  const float4 f0 = ((const float4*)sp)[0];
  const float4 f1 = ((const float4*)sp)[1];

  short8 v;
  v[0] = (short)f2bf(f0.x); v[1] = (short)f2bf(f0.y);
  v[2] = (short)f2bf(f0.z); v[3] = (short)f2bf(f0.w);
  v[4] = (short)f2bf(f1.x); v[5] = (short)f2bf(f1.y);
  v[6] = (short)f2bf(f1.z); v[7] = (short)f2bf(f1.w);

  const unsigned lin = (unsigned)jl * 256u + (unsigned)k8 * 2u;  // byte offset in half
  const unsigned swz = lin ^ ((unsigned)(jl & 7) << 4);          // XOR bits 4..6
  *(short8*)((char*)Wcatb + h * 32768 + swz) = v;
}

// ---------------------------------------------------------------------------
// Kernel 1: P[n][j] = int8 round( val / step_n ),  step_n = rowmax/127 per
// (node, half);  Sc[n][h] = step.
// v5: MFMA operand order SWAPPED -> C[j][node] layout: each lane holds
// node = m16 and 4 CONSECUTIVE j's (quad*4+r) per tile. Epilogue packs 4
// quantized bytes into one dword store: 16 dword-stores/thread (was 64
// byte-stores). Fragments/loads identical (A/B fragment layouts coincide).
// Rowmax reduce is now 2 shfl steps (across quads) instead of 4.
// ---------------------------------------------------------------------------
extern "C" __global__ void __launch_bounds__(256)
node_proj_kernel(const float* __restrict__ feature,
                 const unsigned short* __restrict__ Wcatb,
                 const float* __restrict__ b1,
                 signed char* __restrict__ P,
                 float* __restrict__ Sc)
{
  __shared__ unsigned short Wl[128 * 128]; // 32768 B, swizzled rows of one half
  __shared__ unsigned short Al[BM * LDK];  // 17408 B, padded
  __shared__ float b1l[128];

  const int t = threadIdx.x;
  const int nodeBase = blockIdx.x * BM;

  // ---- issue async W staging for half 0 FIRST (DMA overlaps A conversion) --
  #pragma unroll
  for (int it = 0; it < 8; ++it) {
    int c = t + it * 256;  // 0..2047 chunks of 16 B
    __builtin_amdgcn_global_load_lds(
        (const __attribute__((address_space(1))) void*)((const char*)Wcatb + c * 16),
        (__attribute__((address_space(3))) void*)((char*)Wl + c * 16),
        16, 0, 0);
  }

  // ---- stage A tile (64 nodes x 128 k, fp32 -> bf16) ----
  #pragma unroll
  for (int it = 0; it < 4; ++it) {
    int c  = t + it * 256;       // chunk of 8 elems, 0..1023
    int nl = c >> 4;             // local node 0..63
    int kc = (c & 15) << 3;      // k offset 0..120
    int node = nodeBase + nl;
    float4 f0 = make_float4(0.f, 0.f, 0.f, 0.f);
    float4 f1 = make_float4(0.f, 0.f, 0.f, 0.f);
    if (node < NN) {
      const float* fp = feature + (size_t)node * KF + kc;
      f0 = ((const float4*)fp)[0];
      f1 = ((const float4*)fp)[1];
    }
    short8 v;
    v[0] = (short)f2bf(f0.x); v[1] = (short)f2bf(f0.y);
    v[2] = (short)f2bf(f0.z); v[3] = (short)f2bf(f0.w);
    v[4] = (short)f2bf(f1.x); v[5] = (short)f2bf(f1.y);
    v[6] = (short)f2bf(f1.z); v[7] = (short)f2bf(f1.w);
    *(short8*)&Al[nl * LDK + kc] = v;
  }
  if (t < 128) b1l[t] = b1[t];

  const int wave = t >> 6;
  const int lane = t & 63;
  const int m16  = lane & 15;
  const int quad = lane >> 4;

  short8 a0, a1, a2, a3;
  bool aLoaded = false;

  // This lane's node (C col = m16 after the operand swap)
  const int node = nodeBase + wave * 16 + m16;
  const bool nodeOK = (node < NN);

  for (int half = 0; half < 2; ++half) {
    __syncthreads();  // drains vmcnt: W half + (first iter) A writes visible

    if (!aLoaded) {
      const unsigned short* arow = &Al[(wave * 16 + m16) * LDK + quad * 8];
      a0 = *(const short8*)(arow + 0);
      a1 = *(const short8*)(arow + 32);
      a2 = *(const short8*)(arow + 64);
      a3 = *(const short8*)(arow + 96);
      aLoaded = true;
    }

    floatx4 arr[8];  // statically indexed via unrolled loops (no scratch)

    #pragma unroll
    for (int nt = 0; nt < 8; ++nt) {
      floatx4 acc = {0.f, 0.f, 0.f, 0.f};
      const int jf = nt * 16 + m16;                 // W-fragment row this lane loads
      const unsigned base = (unsigned)jf * 256u + (unsigned)quad * 16u;
      const unsigned msk  = (unsigned)(jf & 7) << 4;
      const char* WlB = (const char*)Wl;
      // SWAPPED operand order: W is the A-operand, nodes are the B-operand.
      // Output: C[j][node], lane holds node=m16, j = nt*16 + quad*4 + r.
      acc = __builtin_amdgcn_mfma_f32_16x16x32_bf16(*(const short8*)(WlB + ((base +   0u) ^ msk)), a0, acc, 0, 0, 0);
      acc = __builtin_amdgcn_mfma_f32_16x16x32_bf16(*(const short8*)(WlB + ((base +  64u) ^ msk)), a1, acc, 0, 0, 0);
      acc = __builtin_amdgcn_mfma_f32_16x16x32_bf16(*(const short8*)(WlB + ((base + 128u) ^ msk)), a2, acc, 0, 0, 0);
      acc = __builtin_amdgcn_mfma_f32_16x16x32_bf16(*(const short8*)(WlB + ((base + 192u) ^ msk)), a3, acc, 0, 0, 0);
      if (half == 0) {
        const int jb = nt * 16 + quad * 4;
        acc[0] += b1l[jb + 0];
        acc[1] += b1l[jb + 1];
        acc[2] += b1l[jb + 2];
        acc[3] += b1l[jb + 3];
      }
      arr[nt] = acc;
    }

    // ---- per-(node, half) max over 128 j's: 32 in-thread + 2 shfl steps ----
    float mx = 0.f;
    #pragma unroll
    for (int nt = 0; nt < 8; ++nt) {
      mx = fmaxf(mx, fmaxf(fmaxf(fabsf(arr[nt][0]), fabsf(arr[nt][1])),
                           fmaxf(fabsf(arr[nt][2]), fabsf(arr[nt][3]))));
    }
    mx = fmaxf(mx, __shfl_xor(mx, 16));
    mx = fmaxf(mx, __shfl_xor(mx, 32));
    const float inv = 127.f / fmaxf(mx, 1e-30f);

    if (quad == 0 && nodeOK)
      Sc[(size_t)node * 2 + half] = mx * (1.f / 127.f);

    // ---- quantize + pack 4 consecutive j-bytes -> one dword store/tile ----
    if (nodeOK) {
      unsigned* prow = (unsigned*)(P + (size_t)node * PC + half * 128 + quad * 4);
      #pragma unroll
      for (int nt = 0; nt < 8; ++nt) {
        const int q0 = (int)rintf(arr[nt][0] * inv);
        const int q1 = (int)rintf(arr[nt][1] * inv);
        const int q2 = (int)rintf(arr[nt][2] * inv);
        const int q3 = (int)rintf(arr[nt][3] * inv);
        const unsigned pw = (unsigned)(q0 & 0xff) |
                            ((unsigned)(q1 & 0xff) << 8) |
                            ((unsigned)(q2 & 0xff) << 16) |
                            ((unsigned)(q3 & 0xff) << 24);
        prow[nt * 4] = pw;   // byte offset nt*16 within the 128-B half-row
      }
    }

    if (half == 0) {
      __syncthreads();  // everyone done reading Wl half 0 before restage
      #pragma unroll
      for (int it = 0; it < 8; ++it) {
        int c = t + it * 256;
        __builtin_amdgcn_global_load_lds(
            (const __attribute__((address_space(1))) void*)((const char*)Wcatb + 32768 + c * 16),
            (__attribute__((address_space(3))) void*)((char*)Wl + c * 16),
            16, 0, 0);
      }
    }
  }
}

// ---------------------------------------------------------------------------
// Kernel 2: out[e] = b2 + sum_j relu(q1[j]*ss + q2[j]*sd) * W2[j]
// (unchanged from round 4 — control group; bytes-bound on the L2-miss path)
// ---------------------------------------------------------------------------
__device__ __forceinline__ float dot8i8(const uint2 a, const uint2 b,
                                        const float sa, const float sb,
                                        const float* __restrict__ w)
{
  float acc = 0.f, x;
  x = fmaxf(fmaf(sb8(a.x, 0), sa, sb8(b.x, 0) * sb), 0.f); acc = fmaf(x, w[0], acc);
  x = fmaxf(fmaf(sb8(a.x, 1), sa, sb8(b.x, 1) * sb), 0.f); acc = fmaf(x, w[1], acc);
  x = fmaxf(fmaf(sb8(a.x, 2), sa, sb8(b.x, 2) * sb), 0.f); acc = fmaf(x, w[2], acc);
  x = fmaxf(fmaf(sb8(a.x, 3), sa, sb8(b.x, 3) * sb), 0.f); acc = fmaf(x, w[3], acc);
  x = fmaxf(fmaf(sb8(a.y, 0), sa, sb8(b.y, 0) * sb), 0.f); acc = fmaf(x, w[4], acc);
  x = fmaxf(fmaf(sb8(a.y, 1), sa, sb8(b.y, 1) * sb), 0.f); acc = fmaf(x, w[5], acc);
  x = fmaxf(fmaf(sb8(a.y, 2), sa, sb8(b.y, 2) * sb), 0.f); acc = fmaf(x, w[6], acc);
  x = fmaxf(fmaf(sb8(a.y, 3), sa, sb8(b.y, 3) * sb), 0.f); acc = fmaf(x, w[7], acc);
  return acc;
}

extern "C" __global__ void __launch_bounds__(256)
edge_score_kernel(const signed char* __restrict__ P,
                  const float* __restrict__ Sc,
                  const int* __restrict__ src,
                  const int* __restrict__ dst,
                  const float* __restrict__ W2,
                  const float* __restrict__ b2,
                  float* __restrict__ out)
{
  const int t    = threadIdx.x;
  const int lane = t & 15;
  const int g    = t >> 4;
  const int e0   = blockIdx.x * 64 + g * 4;
  if (e0 >= NE) return;

  const int4 sv = *(const int4*)(src + e0);
  const int4 dv = *(const int4*)(dst + e0);

  const signed char* Ps = P + lane * 8;          // src half base (+row)
  const signed char* Pd = P + 128 + lane * 8;    // dst half base (+row)

  // 8 independent row gathers in flight (each row-half = 1 cache line).
  const uint2 A0 = *(const uint2*)(Ps + (size_t)sv.x * PC);
  const uint2 B0 = *(const uint2*)(Pd + (size_t)dv.x * PC);
  const uint2 A1 = *(const uint2*)(Ps + (size_t)sv.y * PC);
  const uint2 B1 = *(const uint2*)(Pd + (size_t)dv.y * PC);
  const uint2 A2 = *(const uint2*)(Ps + (size_t)sv.z * PC);
  const uint2 B2 = *(const uint2*)(Pd + (size_t)dv.z * PC);
  const uint2 A3 = *(const uint2*)(Ps + (size_t)sv.w * PC);
  const uint2 B3 = *(const uint2*)(Pd + (size_t)dv.w * PC);

  // per-edge dequant steps (uniform across the 16-lane group -> broadcast)
  const float sA0 = Sc[(size_t)sv.x * 2];
  const float sB0 = Sc[(size_t)dv.x * 2 + 1];
  const float sA1 = Sc[(size_t)sv.y * 2];
  const float sB1 = Sc[(size_t)dv.y * 2 + 1];
  const float sA2 = Sc[(size_t)sv.z * 2];
  const float sB2 = Sc[(size_t)dv.z * 2 + 1];
  const float sA3 = Sc[(size_t)sv.w * 2];
  const float sB3 = Sc[(size_t)dv.w * 2 + 1];

  float w[8];
  {
    const float4 wA = *(const float4*)(W2 + lane * 8);
    const float4 wB = *(const float4*)(W2 + lane * 8 + 4);
    w[0] = wA.x; w[1] = wA.y; w[2] = wA.z; w[3] = wA.w;
    w[4] = wB.x; w[5] = wB.y; w[6] = wB.z; w[7] = wB.w;
  }

  float r0 = dot8i8(A0, B0, sA0, sB0, w);
  float r1 = dot8i8(A1, B1, sA1, sB1, w);
  float r2 = dot8i8(A2, B2, sA2, sB2, w);
  float r3 = dot8i8(A3, B3, sA3, sB3, w);

  r0 += __shfl_xor(r0, 8); r1 += __shfl_xor(r1, 8);
  r2 += __shfl_xor(r2, 8); r3 += __shfl_xor(r3, 8);
  r0 += __shfl_xor(r0, 4); r1 += __shfl_xor(r1, 4);
  r2 += __shfl_xor(r2, 4); r3 += __shfl_xor(r3, 4);
  r0 += __shfl_xor(r0, 2); r1 += __shfl_xor(r1, 2);
  r2 += __shfl_xor(r2, 2); r3 += __shfl_xor(r3, 2);
  r0 += __shfl_xor(r0, 1); r1 += __shfl_xor(r1, 1);
  r2 += __shfl_xor(r2, 1); r3 += __shfl_xor(r3, 1);

  if (lane == 0) {
    const float bb = b2[0];
    float4 o;
    o.x = r0 + bb; o.y = r1 + bb; o.z = r2 + bb; o.w = r3 + bb;
    *(float4*)(out + e0) = o;
  }
}

extern "C" void kernel_launch(void* const* d_in, const int* in_sizes, int n_in,
                              void* d_out, int out_size, void* d_ws, size_t ws_size,
                              hipStream_t stream)
{
  const float* feature = (const float*)d_in[0];
  const int*   src     = (const int*)d_in[1];
  const int*   dst     = (const int*)d_in[2];
  const float* W1      = (const float*)d_in[3];
  const float* b1      = (const float*)d_in[4];
  const float* W2      = (const float*)d_in[5];
  const float* b2      = (const float*)d_in[6];
  float* out = (float*)d_out;
  signed char* P = (signed char*)d_ws;                     // [NN][256] int8, 25.6 MB
  float* Sc = (float*)((char*)d_ws + (size_t)NN * PC);     // [NN][2] steps, 0.8 MB
  unsigned short* Wcatb = (unsigned short*)d_out;          // 64 KB scratch inside out
                                                           // (read before out written)

  dim3 gridW(16);
  wcat_prep_kernel<<<gridW, 256, 0, stream>>>(W1, Wcatb);

  dim3 grid1((NN + BM - 1) / BM);   // 1563 blocks
  node_proj_kernel<<<grid1, 256, 0, stream>>>(feature, Wcatb, b1, P, Sc);

  dim3 grid2((NE + 63) / 64);       // 12500 blocks, 64 edges/block
  edge_score_kernel<<<grid2, 256, 0, stream>>>(P, Sc, src, dst, W2, b2, out);
}

// Round 6
// 144.614 us; speedup vs baseline: 1.0059x; 1.0059x over previous
//
#include <hip/hip_runtime.h>
#include <stdint.h>

typedef short short8 __attribute__((ext_vector_type(8)));
typedef float floatx4 __attribute__((ext_vector_type(4)));

#define NN 100000   // nodes
#define NE 800000   // edges
#define KF 128      // in_feat (K of node GEMM)
#define PC 256      // P row stride in BYTES: [0:128)=src half int8, [128:256)=dst half int8
#define BM 64       // nodes per block in node kernel

// fp32 -> bf16 (RNE)
__device__ __forceinline__ unsigned short f2bf(float x) {
  union { float f; unsigned u; } c; c.f = x;
  unsigned u = c.u + 0x7FFFu + ((c.u >> 16) & 1u);
  return (unsigned short)(u >> 16);
}
// signed byte k of u -> float
__device__ __forceinline__ float sb8(unsigned u, int k) {
  return (float)(signed char)((u >> (8 * k)) & 0xffu);
}
// two float4 -> one short8 of bf16
__device__ __forceinline__ short8 pack8(const float4 u, const float4 v) {
  short8 r;
  r[0] = (short)f2bf(u.x); r[1] = (short)f2bf(u.y);
  r[2] = (short)f2bf(u.z); r[3] = (short)f2bf(u.w);
  r[4] = (short)f2bf(v.x); r[5] = (short)f2bf(v.y);
  r[6] = (short)f2bf(v.z); r[7] = (short)f2bf(v.w);
  return r;
}

// ---------------------------------------------------------------------------
// Kernel 0: one-time W1 (fp32 [128][256]) -> Wcat bf16, concatenated layout,
// PRE-SWIZZLED for linear global_load_lds staging + XOR'd B-fragment reads.
//   Wcat[j][k] = (j<128) ? W1[j][k] : W1[j-128][128+k]
// Output in d_out (read by node_proj before edge_score overwrites d_out).
// ---------------------------------------------------------------------------
extern "C" __global__ void __launch_bounds__(256)
wcat_prep_kernel(const float* __restrict__ W1, unsigned short* __restrict__ Wcatb)
{
  const int idx = blockIdx.x * 256 + threadIdx.x;  // 4096 threads, 8 elems each
  const int j  = idx >> 4;          // Wcat row 0..255
  const int k8 = (idx & 15) << 3;   // k chunk start 0..120

  const int h  = j >> 7;
  const int jl = j & 127;
  const float* sp = W1 + (size_t)jl * 256 + h * 128 + k8;
  const float4 f0 = ((const float4*)sp)[0];
  const float4 f1 = ((const float4*)sp)[1];

  const short8 v = pack8(f0, f1);

  const unsigned lin = (unsigned)jl * 256u + (unsigned)k8 * 2u;  // byte offset in half
  const unsigned swz = lin ^ ((unsigned)(jl & 7) << 4);          // XOR bits 4..6
  *(short8*)((char*)Wcatb + h * 32768 + swz) = v;
}

// ---------------------------------------------------------------------------
// Kernel 1: P[n][j] = int8 round( val / step_n ),  step_n = rowmax/127 per
// (node, half);  Sc[n][h] = step.
// v6: Al LDS tile ELIMINATED. With swapped MFMA operands, each lane's
// B-fragments are its own node-row k-chunks -> loaded directly from global
// (8x float4, line-efficient: wave touches 16 rows x 4 lines, no redundancy)
// and converted in registers. LDS = Wl only (32 KB) -> 4-5 blocks/CU (was 3);
// one less barrier phase; A-load HBM latency overlaps the W half-0 DMA.
// Math bit-identical to v5 (same MFMA sequence, bias-add, quantization).
// ---------------------------------------------------------------------------
extern "C" __global__ void __launch_bounds__(256)
node_proj_kernel(const float* __restrict__ feature,
                 const unsigned short* __restrict__ Wcatb,
                 const float* __restrict__ b1,
                 signed char* __restrict__ P,
                 float* __restrict__ Sc)
{
  __shared__ unsigned short Wl[128 * 128]; // 32768 B, swizzled rows of one half

  const int t    = threadIdx.x;
  const int wave = t >> 6;
  const int lane = t & 63;
  const int m16  = lane & 15;
  const int quad = lane >> 4;
  const int nodeBase = blockIdx.x * BM;
  const int node = nodeBase + wave * 16 + m16;   // this lane's node (C col)
  const bool nodeOK = (node < NN);

  // ---- issue async W staging for half 0 FIRST (DMA overlaps A loads) ----
  #pragma unroll
  for (int it = 0; it < 8; ++it) {
    int c = t + it * 256;  // 0..2047 chunks of 16 B
    __builtin_amdgcn_global_load_lds(
        (const __attribute__((address_space(1))) void*)((const char*)Wcatb + c * 16),
        (__attribute__((address_space(3))) void*)((char*)Wl + c * 16),
        16, 0, 0);
  }

  // ---- A fragments direct from global: node row, k = quad*8 + {0,32,64,96}
  // (OOB lanes read row 0; their garbage stays in C column m16, whose stores
  //  are guarded by nodeOK on this same lane.)
  const float* fp = feature + (size_t)(nodeOK ? node : 0) * KF + quad * 8;
  const float4 f0 = ((const float4*)fp)[0];
  const float4 f1 = ((const float4*)fp)[1];
  const float4 f2 = ((const float4*)(fp + 32))[0];
  const float4 f3 = ((const float4*)(fp + 32))[1];
  const float4 f4 = ((const float4*)(fp + 64))[0];
  const float4 f5 = ((const float4*)(fp + 64))[1];
  const float4 f6 = ((const float4*)(fp + 96))[0];
  const float4 f7 = ((const float4*)(fp + 96))[1];

  const short8 a0 = pack8(f0, f1);
  const short8 a1 = pack8(f2, f3);
  const short8 a2 = pack8(f4, f5);
  const short8 a3 = pack8(f6, f7);

  for (int half = 0; half < 2; ++half) {
    __syncthreads();  // drains vmcnt: this half's W DMA complete & visible

    floatx4 arr[8];  // statically indexed via unrolled loops (no scratch)

    #pragma unroll
    for (int nt = 0; nt < 8; ++nt) {
      floatx4 acc = {0.f, 0.f, 0.f, 0.f};
      const int jf = nt * 16 + m16;                 // W-fragment row this lane loads
      const unsigned base = (unsigned)jf * 256u + (unsigned)quad * 16u;
      const unsigned msk  = (unsigned)(jf & 7) << 4;
      const char* WlB = (const char*)Wl;
      // SWAPPED operand order: W is the A-operand, nodes are the B-operand.
      // Output: C[j][node], lane holds node=m16, j = nt*16 + quad*4 + r.
      acc = __builtin_amdgcn_mfma_f32_16x16x32_bf16(*(const short8*)(WlB + ((base +   0u) ^ msk)), a0, acc, 0, 0, 0);
      acc = __builtin_amdgcn_mfma_f32_16x16x32_bf16(*(const short8*)(WlB + ((base +  64u) ^ msk)), a1, acc, 0, 0, 0);
      acc = __builtin_amdgcn_mfma_f32_16x16x32_bf16(*(const short8*)(WlB + ((base + 128u) ^ msk)), a2, acc, 0, 0, 0);
      acc = __builtin_amdgcn_mfma_f32_16x16x32_bf16(*(const short8*)(WlB + ((base + 192u) ^ msk)), a3, acc, 0, 0, 0);
      if (half == 0) {
        const float4 bv = *(const float4*)(b1 + nt * 16 + quad * 4);  // L1-resident
        acc[0] += bv.x; acc[1] += bv.y; acc[2] += bv.z; acc[3] += bv.w;
      }
      arr[nt] = acc;
    }

    // ---- per-(node, half) max over 128 j's: 32 in-thread + 2 shfl steps ----
    float mx = 0.f;
    #pragma unroll
    for (int nt = 0; nt < 8; ++nt) {
      mx = fmaxf(mx, fmaxf(fmaxf(fabsf(arr[nt][0]), fabsf(arr[nt][1])),
                           fmaxf(fabsf(arr[nt][2]), fabsf(arr[nt][3]))));
    }
    mx = fmaxf(mx, __shfl_xor(mx, 16));
    mx = fmaxf(mx, __shfl_xor(mx, 32));
    const float inv = 127.f / fmaxf(mx, 1e-30f);

    if (quad == 0 && nodeOK)
      Sc[(size_t)node * 2 + half] = mx * (1.f / 127.f);

    // ---- quantize + pack 4 consecutive j-bytes -> one dword store/tile ----
    if (nodeOK) {
      unsigned* prow = (unsigned*)(P + (size_t)node * PC + half * 128 + quad * 4);
      #pragma unroll
      for (int nt = 0; nt < 8; ++nt) {
        const int q0 = (int)rintf(arr[nt][0] * inv);
        const int q1 = (int)rintf(arr[nt][1] * inv);
        const int q2 = (int)rintf(arr[nt][2] * inv);
        const int q3 = (int)rintf(arr[nt][3] * inv);
        const unsigned pw = (unsigned)(q0 & 0xff) |
                            ((unsigned)(q1 & 0xff) << 8) |
                            ((unsigned)(q2 & 0xff) << 16) |
                            ((unsigned)(q3 & 0xff) << 24);
        prow[nt * 4] = pw;   // byte offset nt*16 within the 128-B half-row
      }
    }

    if (half == 0) {
      __syncthreads();  // everyone done reading Wl half 0 before restage
      #pragma unroll
      for (int it = 0; it < 8; ++it) {
        int c = t + it * 256;
        __builtin_amdgcn_global_load_lds(
            (const __attribute__((address_space(1))) void*)((const char*)Wcatb + 32768 + c * 16),
            (__attribute__((address_space(3))) void*)((char*)Wl + c * 16),
            16, 0, 0);
      }
    }
  }
}

// ---------------------------------------------------------------------------
// Kernel 2: out[e] = b2 + sum_j relu(q1[j]*ss + q2[j]*sd) * W2[j]
// (unchanged from round 4 — control group; bytes-bound on the L2-miss path)
// ---------------------------------------------------------------------------
__device__ __forceinline__ float dot8i8(const uint2 a, const uint2 b,
                                        const float sa, const float sb,
                                        const float* __restrict__ w)
{
  float acc = 0.f, x;
  x = fmaxf(fmaf(sb8(a.x, 0), sa, sb8(b.x, 0) * sb), 0.f); acc = fmaf(x, w[0], acc);
  x = fmaxf(fmaf(sb8(a.x, 1), sa, sb8(b.x, 1) * sb), 0.f); acc = fmaf(x, w[1], acc);
  x = fmaxf(fmaf(sb8(a.x, 2), sa, sb8(b.x, 2) * sb), 0.f); acc = fmaf(x, w[2], acc);
  x = fmaxf(fmaf(sb8(a.x, 3), sa, sb8(b.x, 3) * sb), 0.f); acc = fmaf(x, w[3], acc);
  x = fmaxf(fmaf(sb8(a.y, 0), sa, sb8(b.y, 0) * sb), 0.f); acc = fmaf(x, w[4], acc);
  x = fmaxf(fmaf(sb8(a.y, 1), sa, sb8(b.y, 1) * sb), 0.f); acc = fmaf(x, w[5], acc);
  x = fmaxf(fmaf(sb8(a.y, 2), sa, sb8(b.y, 2) * sb), 0.f); acc = fmaf(x, w[6], acc);
  x = fmaxf(fmaf(sb8(a.y, 3), sa, sb8(b.y, 3) * sb), 0.f); acc = fmaf(x, w[7], acc);
  return acc;
}

extern "C" __global__ void __launch_bounds__(256)
edge_score_kernel(const signed char* __restrict__ P,
                  const float* __restrict__ Sc,
                  const int* __restrict__ src,
                  const int* __restrict__ dst,
                  const float* __restrict__ W2,
                  const float* __restrict__ b2,
                  float* __restrict__ out)
{
  const int t    = threadIdx.x;
  const int lane = t & 15;
  const int g    = t >> 4;
  const int e0   = blockIdx.x * 64 + g * 4;
  if (e0 >= NE) return;

  const int4 sv = *(const int4*)(src + e0);
  const int4 dv = *(const int4*)(dst + e0);

  const signed char* Ps = P + lane * 8;          // src half base (+row)
  const signed char* Pd = P + 128 + lane * 8;    // dst half base (+row)

  // 8 independent row gathers in flight (each row-half = 1 cache line).
  const uint2 A0 = *(const uint2*)(Ps + (size_t)sv.x * PC);
  const uint2 B0 = *(const uint2*)(Pd + (size_t)dv.x * PC);
  const uint2 A1 = *(const uint2*)(Ps + (size_t)sv.y * PC);
  const uint2 B1 = *(const uint2*)(Pd + (size_t)dv.y * PC);
  const uint2 A2 = *(const uint2*)(Ps + (size_t)sv.z * PC);
  const uint2 B2 = *(const uint2*)(Pd + (size_t)dv.z * PC);
  const uint2 A3 = *(const uint2*)(Ps + (size_t)sv.w * PC);
  const uint2 B3 = *(const uint2*)(Pd + (size_t)dv.w * PC);

  // per-edge dequant steps (uniform across the 16-lane group -> broadcast)
  const float sA0 = Sc[(size_t)sv.x * 2];
  const float sB0 = Sc[(size_t)dv.x * 2 + 1];
  const float sA1 = Sc[(size_t)sv.y * 2];
  const float sB1 = Sc[(size_t)dv.y * 2 + 1];
  const float sA2 = Sc[(size_t)sv.z * 2];
  const float sB2 = Sc[(size_t)dv.z * 2 + 1];
  const float sA3 = Sc[(size_t)sv.w * 2];
  const float sB3 = Sc[(size_t)dv.w * 2 + 1];

  float w[8];
  {
    const float4 wA = *(const float4*)(W2 + lane * 8);
    const float4 wB = *(const float4*)(W2 + lane * 8 + 4);
    w[0] = wA.x; w[1] = wA.y; w[2] = wA.z; w[3] = wA.w;
    w[4] = wB.x; w[5] = wB.y; w[6] = wB.z; w[7] = wB.w;
  }

  float r0 = dot8i8(A0, B0, sA0, sB0, w);
  float r1 = dot8i8(A1, B1, sA1, sB1, w);
  float r2 = dot8i8(A2, B2, sA2, sB2, w);
  float r3 = dot8i8(A3, B3, sA3, sB3, w);

  r0 += __shfl_xor(r0, 8); r1 += __shfl_xor(r1, 8);
  r2 += __shfl_xor(r2, 8); r3 += __shfl_xor(r3, 8);
  r0 += __shfl_xor(r0, 4); r1 += __shfl_xor(r1, 4);
  r2 += __shfl_xor(r2, 4); r3 += __shfl_xor(r3, 4);
  r0 += __shfl_xor(r0, 2); r1 += __shfl_xor(r1, 2);
  r2 += __shfl_xor(r2, 2); r3 += __shfl_xor(r3, 2);
  r0 += __shfl_xor(r0, 1); r1 += __shfl_xor(r1, 1);
  r2 += __shfl_xor(r2, 1); r3 += __shfl_xor(r3, 1);

  if (lane == 0) {
    const float bb = b2[0];
    float4 o;
    o.x = r0 + bb; o.y = r1 + bb; o.z = r2 + bb; o.w = r3 + bb;
    *(float4*)(out + e0) = o;
  }
}

extern "C" void kernel_launch(void* const* d_in, const int* in_sizes, int n_in,
                              void* d_out, int out_size, void* d_ws, size_t ws_size,
                              hipStream_t stream)
{
  const float* feature = (const float*)d_in[0];
  const int*   src     = (const int*)d_in[1];
  const int*   dst     = (const int*)d_in[2];
  const float* W1      = (const float*)d_in[3];
  const float* b1      = (const float*)d_in[4];
  const float* W2      = (const float*)d_in[5];
  const float* b2      = (const float*)d_in[6];
  float* out = (float*)d_out;
  signed char* P = (signed char*)d_ws;                     // [NN][256] int8, 25.6 MB
  float* Sc = (float*)((char*)d_ws + (size_t)NN * PC);     // [NN][2] steps, 0.8 MB
  unsigned short* Wcatb = (unsigned short*)d_out;          // 64 KB scratch inside out
                                                           // (read before out written)

  dim3 gridW(16);
  wcat_prep_kernel<<<gridW, 256, 0, stream>>>(W1, Wcatb);

  dim3 grid1((NN + BM - 1) / BM);   // 1563 blocks
  node_proj_kernel<<<grid1, 256, 0, stream>>>(feature, Wcatb, b1, P, Sc);

  dim3 grid2((NE + 63) / 64);       // 12500 blocks, 64 edges/block
  edge_score_kernel<<<grid2, 256, 0, stream>>>(P, Sc, src, dst, W2, b2, out);
}